// Round 19
// baseline (5147.446 us; speedup 1.0000x reference)
//
#include <hip/hip_runtime.h>

#define B_ 256
#define D_ 128
#define T_ 1024
#define H_ 64
#define G_ 192
#define TILE_T 64
#define NTILES 16
#define NSLOT 4
#define KC 32
#define WS 194

typedef float f32x4 __attribute__((ext_vector_type(4)));
typedef float f32x2 __attribute__((ext_vector_type(2)));

// d_ws layout: xg ring | pad | prod_flag[256] | cons_flag[256]
#define XG_BYTES  50331648ull                 // 256 * 4slots * 64t * 192g * 4B
#define FLAG_OFF  (XG_BYTES + 8192ull)        // pad absorbs prefetch overrun

// Split-workgroup fused GRU, ONE launch, 512 blocks x 256 threads.
//  blocks 0..255   (scan): 3 waves (gate r/z/n) + 1 barrier-parked wave.
//    Per step: own-gate dot -> slot{x, dot+bias} -> lgkmcnt(0)+s_barrier ->
//    read 2 peer slots (NO poll loop, NO tags) -> replicated pointwise.
//    x comes from the global ring, own row only, 8-deep static prefetch;
//    peers' x arrives through the slot exchange.
//  blocks 256..511 (producers): r18 GEMM -> 4-slot global xg ring in d_ws,
//    paced by device-scope flags (agent acquire/release = cross-XCD safe).
//  Residency proof: 59.9KB LDS -> 2 blocks/CU; 512 blocks = 2x256 all
//  resident -> flag waits cannot deadlock.
// Rationale: r18 refuted issue-contention; r8..r18 invariant ~1200cyc/step
// tracks publish+poll cost (~250cyc, r7->r8 calibrated). s_barrier among 3
// IDENTICAL waves replaces the poll; r17 failed only because variable-duty
// producers sat in the same barrier.
__global__ __launch_bounds__(256) void gru_split(
    const float* __restrict__ lat, const float* __restrict__ hidden_init,
    const float* __restrict__ W_ih, const float* __restrict__ W_hh,
    const float* __restrict__ b_ih, const float* __restrict__ b_hh,
    const float* __restrict__ head_w, const float* __restrict__ head_b,
    float* __restrict__ xg_ring, unsigned* __restrict__ prod_flag,
    unsigned* __restrict__ cons_flag, float* __restrict__ out)
{
    __shared__ float lat_s[D_ * TILE_T];     // 32,768 B (producer blocks)
    __shared__ float w_s[KC * WS];           // 24,832 B (producer blocks)
    __shared__ float h_lds[3][H_];           //    768 B (scan blocks)
    __shared__ float slotv[2][3][H_][2];     //  3,072 B (scan blocks) {x, a}

    const int tid  = threadIdx.x;
    const int lane = tid & 63;
    const int wid  = tid >> 6;

    if (blockIdx.x < B_) {
        // ============================ scan block ============================
        const int b = blockIdx.x;
        if (wid == 3) {   // parked wave: match the 1024 step barriers exactly
            for (int i = 0; i < NTILES * TILE_T; ++i)
                __builtin_amdgcn_s_barrier();
            return;
        }
        __builtin_amdgcn_s_setprio(1);
        const int j   = lane;
        const int row = wid * H_ + j;        // r 0..63 | z 64..127 | n 128..191
        f32x4 w4[16];
        {
            const f32x4* W = (const f32x4*)(W_hh + (size_t)row * H_);
#pragma unroll
            for (int q = 0; q < 16; ++q) w4[q] = W[q];
        }
        asm volatile("" : "+v"(w4[0]), "+v"(w4[1]), "+v"(w4[2]), "+v"(w4[3]),
                          "+v"(w4[4]), "+v"(w4[5]), "+v"(w4[6]), "+v"(w4[7]),
                          "+v"(w4[8]), "+v"(w4[9]), "+v"(w4[10]), "+v"(w4[11]),
                          "+v"(w4[12]), "+v"(w4[13]), "+v"(w4[14]), "+v"(w4[15]));
        const float bias = b_hh[row];
        const float hw   = head_w[j];
        const int o1 = (wid == 0) ? 1 : 0;
        const int o2 = (wid == 2) ? 1 : 2;
        float h = hidden_init[b * H_ + j];

        for (int k = 0; k < NTILES; ++k) {
            while (__hip_atomic_load(&prod_flag[b], __ATOMIC_ACQUIRE,
                                     __HIP_MEMORY_SCOPE_AGENT) < 4u * (unsigned)(k + 1))
                __builtin_amdgcn_s_sleep(2);
            const float* xrow =
                xg_ring + ((size_t)b * NSLOT + (k & 3)) * TILE_T * G_ + row;
            // 8-deep static prefetch ring (rule #20: named regs, no dyn index)
            float r0 = xrow[0 * G_], r1 = xrow[1 * G_], r2 = xrow[2 * G_],
                  r3 = xrow[3 * G_], r4 = xrow[4 * G_], r5 = xrow[5 * G_],
                  r6 = xrow[6 * G_], r7 = xrow[7 * G_];

#define SSTEP(RI, TT) do {                                                    \
            float xv = RI;                                                    \
            RI = xrow[(size_t)((TT) + 8) * G_];  /* overrun lands in pad */   \
            h_lds[wid][j] = h;                   /* in-wave DS order */       \
            const f32x4* h4_ = (const f32x4*)h_lds[wid];                      \
            f32x4 a4 = {0.f, 0.f, 0.f, 0.f};                                  \
            _Pragma("unroll")                                                 \
            for (int q = 0; q < 16; ++q) a4 += w4[q] * h4_[q];                \
            float a = ((a4.x + a4.y) + (a4.z + a4.w)) + bias;                 \
            *(volatile float*)&slotv[(TT) & 1][wid][j][0] = xv;               \
            *(volatile float*)&slotv[(TT) & 1][wid][j][1] = a;                \
            __builtin_amdgcn_sched_barrier(0);                                \
            asm volatile("s_waitcnt lgkmcnt(0)" ::: "memory");                \
            __builtin_amdgcn_s_barrier();                                     \
            __builtin_amdgcn_sched_barrier(0);                                \
            float p1x = *(volatile float*)&slotv[(TT) & 1][o1][j][0];         \
            float p1a = *(volatile float*)&slotv[(TT) & 1][o1][j][1];         \
            float p2x = *(volatile float*)&slotv[(TT) & 1][o2][j][0];         \
            float p2a = *(volatile float*)&slotv[(TT) & 1][o2][j][1];         \
            float xr_, ar_, xz_, az_, xn_, an_;                               \
            if (wid == 0)      { xr_ = xv;  ar_ = a;   xz_ = p1x; az_ = p1a;  \
                                 xn_ = p2x; an_ = p2a; }                      \
            else if (wid == 1) { xr_ = p1x; ar_ = p1a; xz_ = xv;  az_ = a;    \
                                 xn_ = p2x; an_ = p2a; }                      \
            else               { xr_ = p1x; ar_ = p1a; xz_ = p2x; az_ = p2a;  \
                                 xn_ = xv;  an_ = a;   }                      \
            float rr  = __builtin_amdgcn_rcpf(1.f + __expf(-(xr_ + ar_)));    \
            float zz  = __builtin_amdgcn_rcpf(1.f + __expf(-(xz_ + az_)));    \
            float pre = xn_ + rr * an_;                                       \
            float nn  = fmaf(-2.f,                                            \
                             __builtin_amdgcn_rcpf(__expf(2.f * pre) + 1.f),  \
                             1.f);                                            \
            h = fmaf(zz, h - nn, nn);            /* (1-z)n + zh */            \
        } while (0)

            for (int tb = 0; tb < TILE_T; tb += 8) {
                SSTEP(r0, tb + 0); SSTEP(r1, tb + 1);
                SSTEP(r2, tb + 2); SSTEP(r3, tb + 3);
                SSTEP(r4, tb + 4); SSTEP(r5, tb + 5);
                SSTEP(r6, tb + 6); SSTEP(r7, tb + 7);
            }
#undef SSTEP
            if (j == 0)   // each scan wave releases tile (producer waits 3m)
                __hip_atomic_fetch_add(&cons_flag[b], 1u, __ATOMIC_RELEASE,
                                       __HIP_MEMORY_SCOPE_AGENT);
        }

        if (wid == 0) {   // all waves hold identical final h
            out[B_ + b * H_ + j] = h;
            float v = h * hw;
#pragma unroll
            for (int off = 32; off > 0; off >>= 1) v += __shfl_down(v, off);
            if (lane == 0) out[b] = v + head_b[0];
        }
    } else {
        // ========================== producer block ==========================
        const int b  = blockIdx.x - B_;
        const int p  = tid;              // 0..255
        const int tx = p & 7;            // t-sub: t = tx*8 + 2*jj + hh
        const int gy = p >> 3;           // g-sub: g = gy*6 + i
        const float* latb = lat + (size_t)b * (D_ * T_);

        float bias6[6];
#pragma unroll
        for (int i = 0; i < 6; ++i) bias6[i] = b_ih[gy * 6 + i];

        for (int kp = 0; kp < NTILES; ++kp) {
            if (kp >= NSLOT) {   // ring slot reuse: tile kp-4 fully consumed
                while (__hip_atomic_load(&cons_flag[b], __ATOMIC_ACQUIRE,
                                         __HIP_MEMORY_SCOPE_AGENT)
                       < 3u * (unsigned)(kp - NSLOT + 1))
                    __builtin_amdgcn_s_sleep(2);
            }
            __syncthreads();   // prev tile's lat_s/w_s consumed (4 prod waves)

            // stage lat tile [d][t] via b128 both sides
#pragma unroll
            for (int i = 0; i < 8; ++i) {
                int f4 = p + 256 * i;          // [0,2048)
                int d  = f4 >> 4;
                int t4 = (f4 & 15) * 4;
                *(f32x4*)&lat_s[d * 64 + t4] =
                    *(const f32x4*)&latb[(size_t)d * T_ + kp * TILE_T + t4];
            }

            f32x2 acc2[4][6];
#pragma unroll
            for (int jj = 0; jj < 4; ++jj)
#pragma unroll
                for (int i = 0; i < 6; ++i) acc2[jj][i] = f32x2{0.f, 0.f};

            for (int kc = 0; kc < D_; kc += KC) {
                __syncthreads();   // lat_s staged / prev w_s consumed
#pragma unroll
                for (int i = 0; i < (G_ * KC) / 256; ++i) {   // 24/thread
                    int f = p + 256 * i;
                    int g = f >> 5, kk = f & 31;
                    w_s[kk * WS + g] = W_ih[(size_t)g * D_ + kc + kk];
                }
                __syncthreads();   // w_s ready
#pragma unroll 4
                for (int kk = 0; kk < KC; ++kk) {
                    f32x4 l0 = *(const f32x4*)&lat_s[(kc + kk) * 64 + tx * 8];
                    f32x4 l1 = *(const f32x4*)&lat_s[(kc + kk) * 64 + tx * 8 + 4];
                    f32x2 lv2[4] = {f32x2{l0.x, l0.y}, f32x2{l0.z, l0.w},
                                    f32x2{l1.x, l1.y}, f32x2{l1.z, l1.w}};
                    float2 w0 = *(const float2*)&w_s[kk * WS + gy * 6];
                    float2 w1 = *(const float2*)&w_s[kk * WS + gy * 6 + 2];
                    float2 w2 = *(const float2*)&w_s[kk * WS + gy * 6 + 4];
                    float wv[6] = {w0.x, w0.y, w1.x, w1.y, w2.x, w2.y};
#pragma unroll
                    for (int jj = 0; jj < 4; ++jj)
#pragma unroll
                        for (int i = 0; i < 6; ++i)
                            acc2[jj][i] += lv2[jj] * f32x2{wv[i], wv[i]};
                }
            }

            // write tile to GLOBAL ring slot, [t][g]-major (scan reads rows)
            float* rb = xg_ring + ((size_t)b * NSLOT + (kp & 3)) * TILE_T * G_;
#pragma unroll
            for (int i = 0; i < 6; ++i)
#pragma unroll
                for (int jj = 0; jj < 4; ++jj) {
                    rb[(size_t)(tx * 8 + 2 * jj + 0) * G_ + gy * 6 + i] =
                        acc2[jj][i].x + bias6[i];
                    rb[(size_t)(tx * 8 + 2 * jj + 1) * G_ + gy * 6 + i] =
                        acc2[jj][i].y + bias6[i];
                }
            asm volatile("s_waitcnt vmcnt(0)" ::: "memory");
            if ((p & 63) == 0)   // per-wave release: orders THIS wave's stores
                __hip_atomic_fetch_add(&prod_flag[b], 1u, __ATOMIC_RELEASE,
                                       __HIP_MEMORY_SCOPE_AGENT);
        }
    }
}

extern "C" void kernel_launch(void* const* d_in, const int* in_sizes, int n_in,
                              void* d_out, int out_size, void* d_ws, size_t ws_size,
                              hipStream_t stream)
{
    const float* lat   = (const float*)d_in[0];
    const float* hid0  = (const float*)d_in[1];
    const float* W_ih  = (const float*)d_in[2];
    const float* W_hh  = (const float*)d_in[3];
    const float* b_ih  = (const float*)d_in[4];
    const float* b_hh  = (const float*)d_in[5];
    const float* headw = (const float*)d_in[6];
    const float* headb = (const float*)d_in[7];
    float* out = (float*)d_out;

    float*    xg_ring   = (float*)d_ws;
    unsigned* prod_flag = (unsigned*)((char*)d_ws + FLAG_OFF);
    unsigned* cons_flag = (unsigned*)((char*)d_ws + FLAG_OFF + 1024);

    hipMemsetAsync((char*)d_ws + FLAG_OFF, 0, 2048, stream);
    gru_split<<<dim3(2 * B_), dim3(256), 0, stream>>>(
        lat, hid0, W_ih, W_hh, b_ih, b_hh, headw, headb,
        xg_ring, prod_flag, cons_flag, out);
}